// Round 2
// baseline (253.571 us; speedup 1.0000x reference)
//
#include <hip/hip_runtime.h>
#include <cstddef>

// CNOT (dim=2, wires=12, control=0, target=1) on x: (4096, 8192) f32.
//
// U @ x is a pure row permutation: out[i, :] = x[i ^ (((i>>11)&1)<<10), :].
// The permutation decomposes into THREE contiguous block copies:
//   rows with bit11=0 are identity:   out[   0:2048] = x[   0:2048]  (64 MiB)
//   rows with bit11=1 swap bit 10:    out[2048:3072] = x[3072:4096]  (32 MiB)
//                                     out[3072:4096] = x[2048:3072]  (32 MiB)
//
// R5: replace the custom copy kernel with 3x hipMemcpyAsync D2D — the
// rocclr blit kernel is the best-measured copy path on gfx950 (~85% of
// HBM peak per rocprof notes, vs our custom kernel's effective ~4-5 TB/s
// inferred from dur_us minus the two ~79us harness poison fills).
// hipMemcpyAsync(..., stream) is graph-capture-safe per harness rules.
// Floor: 268.4 MB total traffic @ ~6.6 TB/s ≈ 41 us of copy time.

extern "C" void kernel_launch(void* const* d_in, const int* in_sizes, int n_in,
                              void* d_out, int out_size, void* d_ws, size_t ws_size,
                              hipStream_t stream) {
    // d_in[0] = U (4096x4096 f32, never read), d_in[1] = x (4096x8192 f32)
    const float* x = (const float*)d_in[1];
    float* out = (float*)d_out;

    const size_t ROW = 8192;                    // floats per row
    const size_t ROW_B = ROW * sizeof(float);   // 32 KiB per row

    // rows 0..2047: identity
    hipMemcpyAsync(out, x, 2048 * ROW_B, hipMemcpyDeviceToDevice, stream);
    // rows 2048..3071 <- x rows 3072..4095
    hipMemcpyAsync(out + 2048 * ROW, x + 3072 * ROW, 1024 * ROW_B,
                   hipMemcpyDeviceToDevice, stream);
    // rows 3072..4095 <- x rows 2048..3071
    hipMemcpyAsync(out + 3072 * ROW, x + 2048 * ROW, 1024 * ROW_B,
                   hipMemcpyDeviceToDevice, stream);
}

// Round 4
// 241.312 us; speedup vs baseline: 1.0508x; 1.0508x over previous
//
#include <hip/hip_runtime.h>

// CNOT (dim=2, wires=12, control=0, target=1) on x: (4096, 8192) f32.
//
// U @ x for this U is a row permutation: out[i, :] = x[i ^ (((i>>11)&1)<<10), :]
// (flip bit 10 of the row index iff bit 11 is set; involution).
// Pure streaming copy: 128 MiB read + 128 MiB write, zero FLOPs.
// Floor: 268.4 MB @ ~6.3 TB/s achievable = ~43 us of copy.
//
// R7: resubmit of R6 (R3 bench was an infra failure: "container failed
// twice" — no kernel signal). R6 = revert to the R0 kernel (best
// measured, 243.7 us). A/B evidence:
//   R0 nt kernel        243.7 us   <- this file
//   R4 plain kernel     252.8 us   (only diff: no nt hints -> nt is +9 us real)
//   R5 rocclr blit x3   253.6 us   (tuned copy path buys nothing -> copy at floor)
// Nontemporal both directions: streaming with zero reuse; nt stores skip
// L2 dirty-line allocation/writeback (128 MiB stream vs 4 MiB/XCD L2).
// Each block owns 1024 consecutive float4 (16 KiB) of one output row;
// each thread moves 4 float4 strided by 256 lanes: every access is one
// contiguous 1 KiB wave transaction, 4 loads in flight before first store.

typedef float v4f __attribute__((ext_vector_type(4)));

#define NROWS 4096
#define ROW_F4 2048            // 8192 floats / 4 per row
#define BLK_F4 1024            // float4 per block
#define BLOCKS (NROWS * ROW_F4 / BLK_F4)   // 8192

__global__ __launch_bounds__(256) void cnot_perm_kernel(
    const v4f* __restrict__ x, v4f* __restrict__ out) {
    const int row  = blockIdx.x >> 1;            // 2 blocks per row
    const int half = (blockIdx.x & 1) << 10;     // 0 or 1024
    const int src  = row ^ (((row >> 11) & 1) << 10);

    const v4f* sp = x   + ((size_t)src << 11) + half + threadIdx.x;
    v4f*       dp = out + ((size_t)row << 11) + half + threadIdx.x;

    v4f a0 = __builtin_nontemporal_load(sp + 0);
    v4f a1 = __builtin_nontemporal_load(sp + 256);
    v4f a2 = __builtin_nontemporal_load(sp + 512);
    v4f a3 = __builtin_nontemporal_load(sp + 768);
    __builtin_nontemporal_store(a0, dp + 0);
    __builtin_nontemporal_store(a1, dp + 256);
    __builtin_nontemporal_store(a2, dp + 512);
    __builtin_nontemporal_store(a3, dp + 768);
}

extern "C" void kernel_launch(void* const* d_in, const int* in_sizes, int n_in,
                              void* d_out, int out_size, void* d_ws, size_t ws_size,
                              hipStream_t stream) {
    // d_in[0] = U (4096x4096 f32, never read), d_in[1] = x (4096x8192 f32)
    const v4f* x = (const v4f*)d_in[1];
    v4f* out = (v4f*)d_out;
    cnot_perm_kernel<<<BLOCKS, 256, 0, stream>>>(x, out);
}